// Round 1
// baseline (1228.134 us; speedup 1.0000x reference)
//
#include <hip/hip_runtime.h>
#include <hip/hip_bf16.h>

// Problem constants
#define NB   8192   // batch
#define NI   2048   // in features (== H, both layers have Kin=2048)
#define NH   2048   // hidden
#define NO   512    // out
#define KP   10240  // 5*2048 augmented K
#define CHNK 4096   // M-chunk rows
#define BNEPS 1e-5f

typedef short bf16x8 __attribute__((ext_vector_type(8)));
typedef float f32x4 __attribute__((ext_vector_type(4)));
typedef unsigned int u32_g __attribute__((address_space(1)));
typedef unsigned int u32_l __attribute__((address_space(3)));

__device__ __forceinline__ void load_lds16(const void* g, void* l) {
  __builtin_amdgcn_global_load_lds((const u32_g*)g, (u32_l*)l, 16, 0, 0);
}

__device__ __forceinline__ unsigned short f2bf(float f) {
  __hip_bfloat16 h = __float2bfloat16(f);
  unsigned short u;
  __builtin_memcpy(&u, &h, 2);
  return u;
}

// ---------------------------------------------------------------------------
// Build W'[o][k'] with k' = s*Kin + i; s=0: wbase[o][i]; s=1..4: coef[i][o][s]*scaler[o].
// Also acc[o] += sum_i coef[i][o][0]  (T0 == 1 folds into bias).
// coef layout: [Kin][Nout][5]. 64x64 (o x i) tile per block, LDS transpose.
// ---------------------------------------------------------------------------
__global__ __launch_bounds__(256) void build_w_kernel(
    const float* __restrict__ wbase, const float* __restrict__ coef,
    const float* __restrict__ scaler, __hip_bfloat16* __restrict__ Wp,
    float* __restrict__ acc, int Nout, int Kin)
{
  __shared__ float lds0[64][65];                 // d=0 values, padded
  __shared__ __hip_bfloat16 ldsT[64][4][68];     // d=1..4, padded
  const int t = threadIdx.x;
  const int o0 = blockIdx.x * 64;
  const int i0 = blockIdx.y * 64;

  // Phase A: coalesced read of coef tile (d fastest, o mid, i slow)
  for (int r = t; r < 64 * 64 * 5; r += 256) {
    int li = r / 320;
    int rem = r - li * 320;
    int lo = rem / 5;
    int d = rem - lo * 5;
    float v = coef[((size_t)(i0 + li) * Nout + (o0 + lo)) * 5 + d];
    if (d == 0) lds0[lo][li] = v;
    else        ldsT[lo][d - 1][li] = __float2bfloat16(v);
  }
  __syncthreads();

  const size_t Kw = (size_t)5 * Kin;
  // Phase B1: write slots 1..4, i fastest (coalesced)
  for (int r = t; r < 64 * 4 * 64; r += 256) {
    int li = r & 63;
    int d  = (r >> 6) & 3;
    int lo = r >> 8;
    float v = __bfloat162float(ldsT[lo][d][li]) * scaler[o0 + lo];
    Wp[(size_t)(o0 + lo) * Kw + (size_t)(d + 1) * Kin + i0 + li] = __float2bfloat16(v);
  }
  // Phase B2: slot 0 (base weights), fully coalesced copy+convert
  for (int r = t; r < 64 * 64; r += 256) {
    int li = r & 63;
    int lo = r >> 6;
    Wp[(size_t)(o0 + lo) * Kw + i0 + li] =
        __float2bfloat16(wbase[(size_t)(o0 + lo) * Kin + i0 + li]);
  }
  // Phase B3: per-o partial sum of d=0 over this i-tile -> atomic accumulate
  {
    int lo = t >> 2, q = t & 3;
    float s = 0.f;
    #pragma unroll
    for (int j = 0; j < 16; ++j) s += lds0[lo][q * 16 + j];
    s += __shfl_xor(s, 1);
    s += __shfl_xor(s, 2);
    if (q == 0) atomicAdd(&acc[o0 + lo], s);
  }
}

// ---------------------------------------------------------------------------
// A1'[b][k'] for a 4096-row chunk: slot0 = x, slots1..4 = T_d(tanh(x)).
// ---------------------------------------------------------------------------
__global__ __launch_bounds__(256) void build_a1_kernel(
    const float* __restrict__ x, __hip_bfloat16* __restrict__ Ap, int b0)
{
  const size_t idx = ((size_t)blockIdx.x * 256 + threadIdx.x) * 4;
  const size_t row = idx >> 11;           // /2048
  const int i = (int)(idx & 2047);
  const float4 xv = *(const float4*)(x + (size_t)b0 * NI + idx);
  const float xa[4] = {xv.x, xv.y, xv.z, xv.w};
  unsigned short u0[4], u1[4], u2[4], u3[4], u4[4];
  #pragma unroll
  for (int j = 0; j < 4; ++j) {
    float v  = xa[j];
    float tn = tanhf(v);
    float t2 = fmaf(2.f * tn, tn, -1.f);
    float t3 = fmaf(2.f * tn, t2, -tn);
    float t4 = fmaf(2.f * tn, t3, -t2);
    u0[j] = f2bf(v);  u1[j] = f2bf(tn); u2[j] = f2bf(t2);
    u3[j] = f2bf(t3); u4[j] = f2bf(t4);
  }
  __hip_bfloat16* bp = Ap + row * KP + i;
  *(ushort4*)(bp)          = make_ushort4(u0[0], u0[1], u0[2], u0[3]);
  *(ushort4*)(bp + NI)     = make_ushort4(u1[0], u1[1], u1[2], u1[3]);
  *(ushort4*)(bp + 2 * NI) = make_ushort4(u2[0], u2[1], u2[2], u2[3]);
  *(ushort4*)(bp + 3 * NI) = make_ushort4(u3[0], u3[1], u3[2], u3[3]);
  *(ushort4*)(bp + 4 * NI) = make_ushort4(u4[0], u4[1], u4[2], u4[3]);
}

// ---------------------------------------------------------------------------
// A2' chunk: hn = gamma*(h-mu)*rsig + beta; slot0 = hn; slots1..4 = T_d(tanh(hn)).
// ---------------------------------------------------------------------------
__global__ __launch_bounds__(256) void build_a2_kernel(
    const float* __restrict__ h, const float* __restrict__ mu,
    const float* __restrict__ rsig, const float* __restrict__ gam,
    const float* __restrict__ bet, __hip_bfloat16* __restrict__ Ap, int b0)
{
  const size_t idx = ((size_t)blockIdx.x * 256 + threadIdx.x) * 4;
  const size_t row = idx >> 11;
  const int j0 = (int)(idx & 2047);
  const float4 hv  = *(const float4*)(h + (size_t)b0 * NH + idx);
  const float4 muv = *(const float4*)(mu + j0);
  const float4 rsv = *(const float4*)(rsig + j0);
  const float4 gv  = *(const float4*)(gam + j0);
  const float4 bv  = *(const float4*)(bet + j0);
  const float ha[4] = {hv.x, hv.y, hv.z, hv.w};
  const float ma[4] = {muv.x, muv.y, muv.z, muv.w};
  const float ra[4] = {rsv.x, rsv.y, rsv.z, rsv.w};
  const float ga[4] = {gv.x, gv.y, gv.z, gv.w};
  const float ba[4] = {bv.x, bv.y, bv.z, bv.w};
  unsigned short u0[4], u1[4], u2[4], u3[4], u4[4];
  #pragma unroll
  for (int j = 0; j < 4; ++j) {
    float hn = fmaf(ga[j] * (ha[j] - ma[j]), ra[j], ba[j]);
    float tn = tanhf(hn);
    float t2 = fmaf(2.f * tn, tn, -1.f);
    float t3 = fmaf(2.f * tn, t2, -tn);
    float t4 = fmaf(2.f * tn, t3, -t2);
    u0[j] = f2bf(hn); u1[j] = f2bf(tn); u2[j] = f2bf(t2);
    u3[j] = f2bf(t3); u4[j] = f2bf(t4);
  }
  __hip_bfloat16* bp = Ap + row * KP + j0;
  *(ushort4*)(bp)          = make_ushort4(u0[0], u0[1], u0[2], u0[3]);
  *(ushort4*)(bp + NH)     = make_ushort4(u1[0], u1[1], u1[2], u1[3]);
  *(ushort4*)(bp + 2 * NH) = make_ushort4(u2[0], u2[1], u2[2], u2[3]);
  *(ushort4*)(bp + 3 * NH) = make_ushort4(u3[0], u3[1], u3[2], u3[3]);
  *(ushort4*)(bp + 4 * NH) = make_ushort4(u4[0], u4[1], u4[2], u4[3]);
}

// ---------------------------------------------------------------------------
// BatchNorm stats: partial sums over 256-row chunks, then finalize.
// ---------------------------------------------------------------------------
__global__ __launch_bounds__(256) void bn_stats_kernel(
    const float* __restrict__ h, float* __restrict__ psum,
    float* __restrict__ psq)
{
  const int col = blockIdx.x * 256 + threadIdx.x;
  const int r0 = blockIdx.y * 256;
  float s = 0.f, q = 0.f;
  for (int r = 0; r < 256; ++r) {
    float v = h[(size_t)(r0 + r) * NH + col];
    s += v;
    q = fmaf(v, v, q);
  }
  psum[(size_t)blockIdx.y * NH + col] = s;
  psq [(size_t)blockIdx.y * NH + col] = q;
}

__global__ __launch_bounds__(256) void bn_finalize_kernel(
    const float* __restrict__ psum, const float* __restrict__ psq,
    float* __restrict__ mu, float* __restrict__ rsig)
{
  const int j = blockIdx.x * 256 + threadIdx.x;
  float s = 0.f, q = 0.f;
  for (int c = 0; c < 32; ++c) {
    s += psum[(size_t)c * NH + j];
    q += psq [(size_t)c * NH + j];
  }
  const float invB = 1.f / (float)NB;
  float m = s * invB;
  float var = fmaf(q, invB, -m * m);
  mu[j] = m;
  rsig[j] = rsqrtf(var + BNEPS);
}

// ---------------------------------------------------------------------------
// bf16 GEMM, B^T layout: C[m][n] = sum_k A[m][k]*Bm[n][k] + bias(n),
// bias(n) = bb[n] + bs[n]*bacc[n].  m97 structure: BMxBN tile = (MF*32)x128,
// BK=64, 4 waves (2x2), global_load_lds width 16, 16x16x32 bf16 MFMA.
// ---------------------------------------------------------------------------
template<int MF>
__global__ __launch_bounds__(256) void gemm_bt(
    const __hip_bfloat16* __restrict__ A, const __hip_bfloat16* __restrict__ Bm,
    float* __restrict__ C, const float* __restrict__ bb,
    const float* __restrict__ bs, const float* __restrict__ bacc,
    int M, int N, int K)
{
  constexpr int BM = MF * 32;
  __shared__ __attribute__((aligned(16))) __hip_bfloat16 As[BM][64];
  __shared__ __attribute__((aligned(16))) __hip_bfloat16 Bs[128][64];
  const int t = threadIdx.x;
  const int lane = t & 63;
  const int w = t >> 6;
  const int nTN = N >> 7;
  const int m0 = (blockIdx.x / nTN) * BM;
  const int n0 = (blockIdx.x % nTN) * 128;
  const int wr = (w >> 1) * (MF * 16);
  const int wc = (w & 1) * 64;
  const int sr = lane >> 3;        // staging row within 8-row granule group
  const int sc = (lane & 7) * 8;   // staging k element
  const __hip_bfloat16* Ag = A  + (size_t)(m0 + w * (8 * MF) + sr) * K + sc;
  const __hip_bfloat16* Bg = Bm + (size_t)(n0 + w * 32 + sr) * K + sc;

  f32x4 acc[MF][4];
  #pragma unroll
  for (int m = 0; m < MF; ++m)
    #pragma unroll
    for (int n = 0; n < 4; ++n) {
      f32x4 z = {0.f, 0.f, 0.f, 0.f};
      acc[m][n] = z;
    }

  const int fr = lane & 15;
  const int kg = (lane >> 4) * 8;

  for (int kt = 0; kt < K; kt += 64) {
    #pragma unroll
    for (int c = 0; c < MF; ++c)
      load_lds16(Ag + (size_t)c * 8 * K + kt, &As[w * 8 * MF + c * 8][0]);
    #pragma unroll
    for (int c = 0; c < 4; ++c)
      load_lds16(Bg + (size_t)c * 8 * K + kt, &Bs[w * 32 + c * 8][0]);
    __syncthreads();
    #pragma unroll
    for (int kk = 0; kk < 2; ++kk) {
      bf16x8 af[MF], bfr[4];
      #pragma unroll
      for (int m = 0; m < MF; ++m)
        af[m] = *(const bf16x8*)&As[wr + m * 16 + fr][kk * 32 + kg];
      #pragma unroll
      for (int n = 0; n < 4; ++n)
        bfr[n] = *(const bf16x8*)&Bs[wc + n * 16 + fr][kk * 32 + kg];
      #pragma unroll
      for (int m = 0; m < MF; ++m)
        #pragma unroll
        for (int n = 0; n < 4; ++n)
          acc[m][n] = __builtin_amdgcn_mfma_f32_16x16x32_bf16(
              af[m], bfr[n], acc[m][n], 0, 0, 0);
    }
    __syncthreads();
  }

  const int cr = (lane >> 4) * 4;
  const int cc = lane & 15;
  #pragma unroll
  for (int n = 0; n < 4; ++n) {
    const int col = n0 + wc + n * 16 + cc;
    const float bias = bb[col] + bs[col] * bacc[col];
    #pragma unroll
    for (int m = 0; m < MF; ++m) {
      float* Cp = C + (size_t)(m0 + wr + m * 16 + cr) * N + col;
      #pragma unroll
      for (int r = 0; r < 4; ++r)
        Cp[(size_t)r * N] = acc[m][n][r] + bias;
    }
  }
}

// ---------------------------------------------------------------------------
extern "C" void kernel_launch(void* const* d_in, const int* in_sizes, int n_in,
                              void* d_out, int out_size, void* d_ws, size_t ws_size,
                              hipStream_t stream) {
  (void)in_sizes; (void)n_in; (void)out_size; (void)ws_size;
  const float* x   = (const float*)d_in[0];
  const float* w1  = (const float*)d_in[1];
  const float* b1  = (const float*)d_in[2];
  const float* c1  = (const float*)d_in[3];
  const float* s1  = (const float*)d_in[4];
  const float* gam = (const float*)d_in[5];
  const float* bet = (const float*)d_in[6];
  const float* w2  = (const float*)d_in[7];
  const float* b2  = (const float*)d_in[8];
  const float* c2  = (const float*)d_in[9];
  const float* s2  = (const float*)d_in[10];
  float* out = (float*)d_out;

  char* ws = (char*)d_ws;
  __hip_bfloat16* Ap = (__hip_bfloat16*)(ws);                    // 83,886,080 B
  __hip_bfloat16* Wp = (__hip_bfloat16*)(ws + 83886080ULL);      // 41,943,040 B
  float* h    = (float*)(ws + 125829120ULL);                     // 67,108,864 B
  float* acc1 = (float*)(ws + 192937984ULL);                     // 8,192 B
  float* acc2 = (float*)(ws + 192946176ULL);                     // 2,048 B
  float* psum = (float*)(ws + 192948224ULL);                     // 262,144 B
  float* psq  = (float*)(ws + 193210368ULL);                     // 262,144 B
  float* mu   = (float*)(ws + 193472512ULL);                     // 8,192 B
  float* rsig = (float*)(ws + 193480704ULL);                     // 8,192 B

  dim3 blk(256);

  // zero the bias accumulators (acc1 and acc2 are contiguous)
  hipMemsetAsync(acc1, 0, 8192 + 2048, stream);

  // Layer 1 weights + bias-acc
  build_w_kernel<<<dim3(NH / 64, NI / 64), blk, 0, stream>>>(w1, c1, s1, Wp, acc1, NH, NI);

  // Layer 1 GEMM over 2 chunks of 4096 rows
  for (int ch = 0; ch < 2; ++ch) {
    int b0 = ch * CHNK;
    build_a1_kernel<<<(CHNK * NI / 4) / 256, blk, 0, stream>>>(x, Ap, b0);
    gemm_bt<4><<<(CHNK / 128) * (NH / 128), blk, 0, stream>>>(
        Ap, Wp, h + (size_t)b0 * NH, b1, s1, acc1, CHNK, NH, KP);
  }

  // BatchNorm statistics
  bn_stats_kernel<<<dim3(NH / 256, 32), blk, 0, stream>>>(h, psum, psq);
  bn_finalize_kernel<<<NH / 256, blk, 0, stream>>>(psum, psq, mu, rsig);

  // Layer 2 weights + bias-acc (Wp reused after layer-1 GEMMs complete)
  build_w_kernel<<<dim3(NO / 64, NH / 64), blk, 0, stream>>>(w2, c2, s2, Wp, acc2, NO, NH);

  // Layer 2 GEMM over 2 chunks (BM=64 so grid stays at 256 blocks)
  for (int ch = 0; ch < 2; ++ch) {
    int b0 = ch * CHNK;
    build_a2_kernel<<<(CHNK * NH / 4) / 256, blk, 0, stream>>>(h, mu, rsig, gam, bet, Ap, b0);
    gemm_bt<2><<<(CHNK / 64) * (NO / 128), blk, 0, stream>>>(
        Ap, Wp, out + (size_t)b0 * NO, b2, s2, acc2, CHNK, NO, KP);
  }
}

// Round 2
// 1109.683 us; speedup vs baseline: 1.1067x; 1.1067x over previous
//
#include <hip/hip_runtime.h>
#include <hip/hip_bf16.h>

// Problem constants
#define NB   8192   // batch
#define NI   2048   // in features
#define NH   2048   // hidden
#define NO   512    // out
#define KP   10240  // 5*2048 augmented K
#define CHNK 4096   // M-chunk rows (fallback path)
#define BNEPS 1e-5f

typedef short bf16x8 __attribute__((ext_vector_type(8)));
typedef float f32x4 __attribute__((ext_vector_type(4)));
typedef unsigned int u32_g __attribute__((address_space(1)));
typedef unsigned int u32_l __attribute__((address_space(3)));

__device__ __forceinline__ void load_lds16(const void* g, void* l) {
  __builtin_amdgcn_global_load_lds((const u32_g*)g, (u32_l*)l, 16, 0, 0);
}

__device__ __forceinline__ unsigned short f2bf(float f) {
  __hip_bfloat16 h = __float2bfloat16(f);
  unsigned short u;
  __builtin_memcpy(&u, &h, 2);
  return u;
}

// ---------------------------------------------------------------------------
// Build W'[o][k'] with k' = s*Kin + i; s=0: wbase[o][i]; s=1..4: coef[i][o][s]*scaler[o].
// Also acc[o] += sum_i coef[i][o][0]  (T0 == 1 folds into bias).
// ---------------------------------------------------------------------------
__global__ __launch_bounds__(256) void build_w_kernel(
    const float* __restrict__ wbase, const float* __restrict__ coef,
    const float* __restrict__ scaler, __hip_bfloat16* __restrict__ Wp,
    float* __restrict__ acc, int Nout, int Kin)
{
  __shared__ float lds0[64][65];
  __shared__ __hip_bfloat16 ldsT[64][4][68];
  const int t = threadIdx.x;
  const int o0 = blockIdx.x * 64;
  const int i0 = blockIdx.y * 64;

  for (int r = t; r < 64 * 64 * 5; r += 256) {
    int li = r / 320;
    int rem = r - li * 320;
    int lo = rem / 5;
    int d = rem - lo * 5;
    float v = coef[((size_t)(i0 + li) * Nout + (o0 + lo)) * 5 + d];
    if (d == 0) lds0[lo][li] = v;
    else        ldsT[lo][d - 1][li] = __float2bfloat16(v);
  }
  __syncthreads();

  const size_t Kw = (size_t)5 * Kin;
  for (int r = t; r < 64 * 4 * 64; r += 256) {
    int li = r & 63;
    int d  = (r >> 6) & 3;
    int lo = r >> 8;
    float v = __bfloat162float(ldsT[lo][d][li]) * scaler[o0 + lo];
    Wp[(size_t)(o0 + lo) * Kw + (size_t)(d + 1) * Kin + i0 + li] = __float2bfloat16(v);
  }
  for (int r = t; r < 64 * 64; r += 256) {
    int li = r & 63;
    int lo = r >> 6;
    Wp[(size_t)(o0 + lo) * Kw + i0 + li] =
        __float2bfloat16(wbase[(size_t)(o0 + lo) * Kin + i0 + li]);
  }
  {
    int lo = t >> 2, q = t & 3;
    float s = 0.f;
    #pragma unroll
    for (int j = 0; j < 16; ++j) s += lds0[lo][q * 16 + j];
    s += __shfl_xor(s, 1);
    s += __shfl_xor(s, 2);
    if (q == 0) atomicAdd(&acc[o0 + lo], s);
  }
}

// ---------------------------------------------------------------------------
// A1'[b][k']: slot0 = x, slots1..4 = T_d(tanh(x)).  Grid covers `rows` rows.
// ---------------------------------------------------------------------------
__global__ __launch_bounds__(256) void build_a1_kernel(
    const float* __restrict__ x, __hip_bfloat16* __restrict__ Ap, int b0)
{
  const size_t idx = ((size_t)blockIdx.x * 256 + threadIdx.x) * 4;
  const size_t row = idx >> 11;
  const int i = (int)(idx & 2047);
  const float4 xv = *(const float4*)(x + (size_t)b0 * NI + idx);
  const float xa[4] = {xv.x, xv.y, xv.z, xv.w};
  unsigned short u0[4], u1[4], u2[4], u3[4], u4[4];
  #pragma unroll
  for (int j = 0; j < 4; ++j) {
    float v  = xa[j];
    float tn = tanhf(v);
    float t2 = fmaf(2.f * tn, tn, -1.f);
    float t3 = fmaf(2.f * tn, t2, -tn);
    float t4 = fmaf(2.f * tn, t3, -t2);
    u0[j] = f2bf(v);  u1[j] = f2bf(tn); u2[j] = f2bf(t2);
    u3[j] = f2bf(t3); u4[j] = f2bf(t4);
  }
  __hip_bfloat16* bp = Ap + row * KP + i;
  *(ushort4*)(bp)          = make_ushort4(u0[0], u0[1], u0[2], u0[3]);
  *(ushort4*)(bp + NI)     = make_ushort4(u1[0], u1[1], u1[2], u1[3]);
  *(ushort4*)(bp + 2 * NI) = make_ushort4(u2[0], u2[1], u2[2], u2[3]);
  *(ushort4*)(bp + 3 * NI) = make_ushort4(u3[0], u3[1], u3[2], u3[3]);
  *(ushort4*)(bp + 4 * NI) = make_ushort4(u4[0], u4[1], u4[2], u4[3]);
}

// ---------------------------------------------------------------------------
// A2': hn = gamma*(h-mu)*rsig + beta; slot0 = hn; slots1..4 = T_d(tanh(hn)).
// h is bf16.
// ---------------------------------------------------------------------------
__global__ __launch_bounds__(256) void build_a2_kernel(
    const __hip_bfloat16* __restrict__ h, const float* __restrict__ mu,
    const float* __restrict__ rsig, const float* __restrict__ gam,
    const float* __restrict__ bet, __hip_bfloat16* __restrict__ Ap, int b0)
{
  const size_t idx = ((size_t)blockIdx.x * 256 + threadIdx.x) * 4;
  const size_t row = idx >> 11;
  const int j0 = (int)(idx & 2047);
  const ushort4 hv = *(const ushort4*)(h + (size_t)b0 * NH + idx);
  const float4 muv = *(const float4*)(mu + j0);
  const float4 rsv = *(const float4*)(rsig + j0);
  const float4 gv  = *(const float4*)(gam + j0);
  const float4 bv  = *(const float4*)(bet + j0);
  unsigned short hu[4] = {hv.x, hv.y, hv.z, hv.w};
  const float ma[4] = {muv.x, muv.y, muv.z, muv.w};
  const float ra[4] = {rsv.x, rsv.y, rsv.z, rsv.w};
  const float ga[4] = {gv.x, gv.y, gv.z, gv.w};
  const float ba[4] = {bv.x, bv.y, bv.z, bv.w};
  unsigned short u0[4], u1[4], u2[4], u3[4], u4[4];
  #pragma unroll
  for (int j = 0; j < 4; ++j) {
    __hip_bfloat16 hb;
    __builtin_memcpy(&hb, &hu[j], 2);
    float hv_f = __bfloat162float(hb);
    float hn = fmaf(ga[j] * (hv_f - ma[j]), ra[j], ba[j]);
    float tn = tanhf(hn);
    float t2 = fmaf(2.f * tn, tn, -1.f);
    float t3 = fmaf(2.f * tn, t2, -tn);
    float t4 = fmaf(2.f * tn, t3, -t2);
    u0[j] = f2bf(hn); u1[j] = f2bf(tn); u2[j] = f2bf(t2);
    u3[j] = f2bf(t3); u4[j] = f2bf(t4);
  }
  __hip_bfloat16* bp = Ap + row * KP + j0;
  *(ushort4*)(bp)          = make_ushort4(u0[0], u0[1], u0[2], u0[3]);
  *(ushort4*)(bp + NH)     = make_ushort4(u1[0], u1[1], u1[2], u1[3]);
  *(ushort4*)(bp + 2 * NH) = make_ushort4(u2[0], u2[1], u2[2], u2[3]);
  *(ushort4*)(bp + 3 * NH) = make_ushort4(u3[0], u3[1], u3[2], u3[3]);
  *(ushort4*)(bp + 4 * NH) = make_ushort4(u4[0], u4[1], u4[2], u4[3]);
}

// ---------------------------------------------------------------------------
// BatchNorm stats over bf16 h.
// ---------------------------------------------------------------------------
__global__ __launch_bounds__(256) void bn_stats_kernel(
    const __hip_bfloat16* __restrict__ h, float* __restrict__ psum,
    float* __restrict__ psq)
{
  const int col = blockIdx.x * 256 + threadIdx.x;
  const int r0 = blockIdx.y * 256;
  float s = 0.f, q = 0.f;
  for (int r = 0; r < 256; ++r) {
    float v = __bfloat162float(h[(size_t)(r0 + r) * NH + col]);
    s += v;
    q = fmaf(v, v, q);
  }
  psum[(size_t)blockIdx.y * NH + col] = s;
  psq [(size_t)blockIdx.y * NH + col] = q;
}

__global__ __launch_bounds__(256) void bn_finalize_kernel(
    const float* __restrict__ psum, const float* __restrict__ psq,
    float* __restrict__ mu, float* __restrict__ rsig)
{
  const int j = blockIdx.x * 256 + threadIdx.x;
  float s = 0.f, q = 0.f;
  for (int c = 0; c < 32; ++c) {
    s += psum[(size_t)c * NH + j];
    q += psq [(size_t)c * NH + j];
  }
  const float invB = 1.f / (float)NB;
  float m = s * invB;
  float var = fmaf(q, invB, -m * m);
  mu[j] = m;
  rsig[j] = rsqrtf(var + BNEPS);
}

// ---------------------------------------------------------------------------
// out[b][o] = b2[o] + s2[o]*acc2[o]   (bias pre-init for split-K atomic GEMM2)
// ---------------------------------------------------------------------------
__global__ __launch_bounds__(256) void bias_init_kernel(
    float* __restrict__ out, const float* __restrict__ bb,
    const float* __restrict__ bs, const float* __restrict__ bacc)
{
  const size_t idx = ((size_t)blockIdx.x * 256 + threadIdx.x) * 4;
  const int col = (int)(idx & (NO - 1));
  const float4 b = *(const float4*)(bb + col);
  const float4 s = *(const float4*)(bs + col);
  const float4 a = *(const float4*)(bacc + col);
  float4 o;
  o.x = b.x + s.x * a.x; o.y = b.y + s.y * a.y;
  o.z = b.z + s.z * a.z; o.w = b.w + s.w * a.w;
  *(float4*)(out + idx) = o;
}

// ---------------------------------------------------------------------------
// GEMM1: C(bf16) [m][n] = sum_k A[m][k]*Bm[n][k] + bias(n).
// m97 structure: tile (MF*32)x128, BK=64, 4 waves, global_load_lds w16,
// XCD-bijective block swizzle (grid divisible by 8).
// ---------------------------------------------------------------------------
template<int MF>
__global__ __launch_bounds__(256) void gemm_bt_h(
    const __hip_bfloat16* __restrict__ A, const __hip_bfloat16* __restrict__ Bm,
    __hip_bfloat16* __restrict__ C, const float* __restrict__ bb,
    const float* __restrict__ bs, const float* __restrict__ bacc,
    int N, int K)
{
  constexpr int BM = MF * 32;
  __shared__ __attribute__((aligned(16))) __hip_bfloat16 As[BM][64];
  __shared__ __attribute__((aligned(16))) __hip_bfloat16 Bs[128][64];
  const int t = threadIdx.x;
  const int lane = t & 63;
  const int w = t >> 6;
  const int swz = ((int)blockIdx.x & 7) * ((int)gridDim.x >> 3) + ((int)blockIdx.x >> 3);
  const int nTN = N >> 7;
  const int m0 = (swz / nTN) * BM;
  const int n0 = (swz % nTN) * 128;
  const int wr = (w >> 1) * (MF * 16);
  const int wc = (w & 1) * 64;
  const int sr = lane >> 3;
  const int sc = (lane & 7) * 8;
  const __hip_bfloat16* Ag = A  + (size_t)(m0 + w * (8 * MF) + sr) * K + sc;
  const __hip_bfloat16* Bg = Bm + (size_t)(n0 + w * 32 + sr) * K + sc;

  f32x4 acc[MF][4];
  #pragma unroll
  for (int m = 0; m < MF; ++m)
    #pragma unroll
    for (int n = 0; n < 4; ++n) {
      f32x4 z = {0.f, 0.f, 0.f, 0.f};
      acc[m][n] = z;
    }

  const int fr = lane & 15;
  const int kg = (lane >> 4) * 8;

  for (int kt = 0; kt < K; kt += 64) {
    #pragma unroll
    for (int c = 0; c < MF; ++c)
      load_lds16(Ag + (size_t)c * 8 * K + kt, &As[w * 8 * MF + c * 8][0]);
    #pragma unroll
    for (int c = 0; c < 4; ++c)
      load_lds16(Bg + (size_t)c * 8 * K + kt, &Bs[w * 32 + c * 8][0]);
    __syncthreads();
    #pragma unroll
    for (int kk = 0; kk < 2; ++kk) {
      bf16x8 af[MF], bfr[4];
      #pragma unroll
      for (int m = 0; m < MF; ++m)
        af[m] = *(const bf16x8*)&As[wr + m * 16 + fr][kk * 32 + kg];
      #pragma unroll
      for (int n = 0; n < 4; ++n)
        bfr[n] = *(const bf16x8*)&Bs[wc + n * 16 + fr][kk * 32 + kg];
      #pragma unroll
      for (int m = 0; m < MF; ++m)
        #pragma unroll
        for (int n = 0; n < 4; ++n)
          acc[m][n] = __builtin_amdgcn_mfma_f32_16x16x32_bf16(
              af[m], bfr[n], acc[m][n], 0, 0, 0);
    }
    __syncthreads();
  }

  const int cr = (lane >> 4) * 4;
  const int cc = lane & 15;
  #pragma unroll
  for (int n = 0; n < 4; ++n) {
    const int col = n0 + wc + n * 16 + cc;
    const float bias = bb[col] + bs[col] * bacc[col];
    #pragma unroll
    for (int m = 0; m < MF; ++m) {
      __hip_bfloat16* Cp = C + (size_t)(m0 + wr + m * 16 + cr) * N + col;
      #pragma unroll
      for (int r = 0; r < 4; ++r)
        Cp[(size_t)r * N] = __float2bfloat16(acc[m][n][r] + bias);
    }
  }
}

// ---------------------------------------------------------------------------
// GEMM2: split-K, atomicAdd f32 into pre-biased C.
// Grid = nsplit * blocks_per_split (bps = 1<<lg2bps), both divisible by 8.
// ---------------------------------------------------------------------------
template<int MF>
__global__ __launch_bounds__(256) void gemm_bt_atomic(
    const __hip_bfloat16* __restrict__ A, const __hip_bfloat16* __restrict__ Bm,
    float* __restrict__ C, int N, int Kstride, int K2, int lg2bps)
{
  constexpr int BM = MF * 32;
  __shared__ __attribute__((aligned(16))) __hip_bfloat16 As[BM][64];
  __shared__ __attribute__((aligned(16))) __hip_bfloat16 Bs[128][64];
  const int t = threadIdx.x;
  const int lane = t & 63;
  const int w = t >> 6;
  const int swz = ((int)blockIdx.x & 7) * ((int)gridDim.x >> 3) + ((int)blockIdx.x >> 3);
  const int split = swz >> lg2bps;
  const int l = swz & ((1 << lg2bps) - 1);
  const int nTN = N >> 7;
  const int m0 = (l / nTN) * BM;
  const int n0 = (l % nTN) * 128;
  const int k0 = split * K2;
  const int wr = (w >> 1) * (MF * 16);
  const int wc = (w & 1) * 64;
  const int sr = lane >> 3;
  const int sc = (lane & 7) * 8;
  const __hip_bfloat16* Ag = A  + (size_t)(m0 + w * (8 * MF) + sr) * Kstride + sc;
  const __hip_bfloat16* Bg = Bm + (size_t)(n0 + w * 32 + sr) * Kstride + sc;

  f32x4 acc[MF][4];
  #pragma unroll
  for (int m = 0; m < MF; ++m)
    #pragma unroll
    for (int n = 0; n < 4; ++n) {
      f32x4 z = {0.f, 0.f, 0.f, 0.f};
      acc[m][n] = z;
    }

  const int fr = lane & 15;
  const int kg = (lane >> 4) * 8;

  for (int kt = k0; kt < k0 + K2; kt += 64) {
    #pragma unroll
    for (int c = 0; c < MF; ++c)
      load_lds16(Ag + (size_t)c * 8 * Kstride + kt, &As[w * 8 * MF + c * 8][0]);
    #pragma unroll
    for (int c = 0; c < 4; ++c)
      load_lds16(Bg + (size_t)c * 8 * Kstride + kt, &Bs[w * 32 + c * 8][0]);
    __syncthreads();
    #pragma unroll
    for (int kk = 0; kk < 2; ++kk) {
      bf16x8 af[MF], bfr[4];
      #pragma unroll
      for (int m = 0; m < MF; ++m)
        af[m] = *(const bf16x8*)&As[wr + m * 16 + fr][kk * 32 + kg];
      #pragma unroll
      for (int n = 0; n < 4; ++n)
        bfr[n] = *(const bf16x8*)&Bs[wc + n * 16 + fr][kk * 32 + kg];
      #pragma unroll
      for (int m = 0; m < MF; ++m)
        #pragma unroll
        for (int n = 0; n < 4; ++n)
          acc[m][n] = __builtin_amdgcn_mfma_f32_16x16x32_bf16(
              af[m], bfr[n], acc[m][n], 0, 0, 0);
    }
    __syncthreads();
  }

  const int cr = (lane >> 4) * 4;
  const int cc = lane & 15;
  #pragma unroll
  for (int n = 0; n < 4; ++n) {
    const int col = n0 + wc + n * 16 + cc;
    #pragma unroll
    for (int m = 0; m < MF; ++m) {
      float* Cp = C + (size_t)(m0 + wr + m * 16 + cr) * N + col;
      #pragma unroll
      for (int r = 0; r < 4; ++r)
        atomicAdd(&Cp[(size_t)r * N], acc[m][n][r]);
    }
  }
}

// ---------------------------------------------------------------------------
extern "C" void kernel_launch(void* const* d_in, const int* in_sizes, int n_in,
                              void* d_out, int out_size, void* d_ws, size_t ws_size,
                              hipStream_t stream) {
  (void)in_sizes; (void)n_in; (void)out_size;
  const float* x   = (const float*)d_in[0];
  const float* w1  = (const float*)d_in[1];
  const float* b1  = (const float*)d_in[2];
  const float* c1  = (const float*)d_in[3];
  const float* s1  = (const float*)d_in[4];
  const float* gam = (const float*)d_in[5];
  const float* bet = (const float*)d_in[6];
  const float* w2  = (const float*)d_in[7];
  const float* b2  = (const float*)d_in[8];
  const float* c2  = (const float*)d_in[9];
  const float* s2  = (const float*)d_in[10];
  float* out = (float*)d_out;

  // Workspace layout (full path: Ap covers all 8192 rows; fallback: 4096)
  const bool full = ws_size >= 243820544ULL;
  const size_t apBytes = full ? 167772160ULL : 83886080ULL;
  char* ws = (char*)d_ws;
  __hip_bfloat16* Ap = (__hip_bfloat16*)ws;
  __hip_bfloat16* Wp = (__hip_bfloat16*)(ws + apBytes);
  __hip_bfloat16* hb = (__hip_bfloat16*)(ws + apBytes + 41943040ULL);
  char* tail = ws + apBytes + 41943040ULL + 33554432ULL;
  float* acc1 = (float*)(tail);
  float* acc2 = (float*)(tail + 8192);
  float* psum = (float*)(tail + 10240);
  float* psq  = (float*)(tail + 272384);
  float* mu   = (float*)(tail + 534528);
  float* rsig = (float*)(tail + 542720);

  dim3 blk(256);
  hipMemsetAsync(acc1, 0, 8192 + 2048, stream);

  // Layer 1 weights + bias-acc
  build_w_kernel<<<dim3(NH / 64, NI / 64), blk, 0, stream>>>(w1, c1, s1, Wp, acc1, NH, NI);

  if (full) {
    build_a1_kernel<<<(NB * NI / 4) / 256, blk, 0, stream>>>(x, Ap, 0);
    gemm_bt_h<4><<<(NB / 128) * (NH / 128), blk, 0, stream>>>(
        Ap, Wp, hb, b1, s1, acc1, NH, KP);
  } else {
    for (int ch = 0; ch < 2; ++ch) {
      int b0 = ch * CHNK;
      build_a1_kernel<<<(CHNK * NI / 4) / 256, blk, 0, stream>>>(x, Ap, b0);
      gemm_bt_h<4><<<(CHNK / 128) * (NH / 128), blk, 0, stream>>>(
          Ap, Wp, hb + (size_t)b0 * NH, b1, s1, acc1, NH, KP);
    }
  }

  // BatchNorm statistics
  bn_stats_kernel<<<dim3(NH / 256, 32), blk, 0, stream>>>(hb, psum, psq);
  bn_finalize_kernel<<<NH / 256, blk, 0, stream>>>(psum, psq, mu, rsig);

  // Layer 2 weights + bias-acc (Wp reused)
  build_w_kernel<<<dim3(NO / 64, NH / 64), blk, 0, stream>>>(w2, c2, s2, Wp, acc2, NO, NH);

  // Pre-init out with bias, then split-K=4 atomic GEMM2
  bias_init_kernel<<<(NB * NO / 4) / 256, blk, 0, stream>>>(out, b2, s2, acc2);

  if (full) {
    build_a2_kernel<<<(NB * NH / 4) / 256, blk, 0, stream>>>(hb, mu, rsig, gam, bet, Ap, 0);
    // 4 splits x 256 blocks = 1024; bps=256 -> lg2bps=8; K2 = 2560
    gemm_bt_atomic<4><<<4 * (NB / 128) * (NO / 128), blk, 0, stream>>>(
        Ap, Wp, out, NO, KP, KP / 4, 8);
  } else {
    for (int ch = 0; ch < 2; ++ch) {
      int b0 = ch * CHNK;
      build_a2_kernel<<<(CHNK * NH / 4) / 256, blk, 0, stream>>>(hb, mu, rsig, gam, bet, Ap, b0);
      // 4 splits x 128 blocks = 512; lg2bps=7
      gemm_bt_atomic<4><<<4 * (CHNK / 128) * (NO / 128), blk, 0, stream>>>(
          Ap, Wp, out + (size_t)b0 * NO, NO, KP, KP / 4, 7);
    }
  }
}

// Round 4
// 906.975 us; speedup vs baseline: 1.3541x; 1.2235x over previous
//
#include <hip/hip_runtime.h>
#include <hip/hip_bf16.h>

// Problem constants
#define NB   8192   // batch
#define NI   2048   // in features
#define NH   2048   // hidden
#define NO   512    // out
#define KP   10240  // 5*2048 augmented K
#define CHNK 4096   // M-chunk rows (fallback path)
#define BNEPS 1e-5f

typedef short bf16x8 __attribute__((ext_vector_type(8)));
typedef float f32x4 __attribute__((ext_vector_type(4)));
typedef unsigned int u32_g __attribute__((address_space(1)));
typedef unsigned int u32_l __attribute__((address_space(3)));

__device__ __forceinline__ void load_lds16(const void* g, void* l) {
  __builtin_amdgcn_global_load_lds((const u32_g*)g, (u32_l*)l, 16, 0, 0);
}

__device__ __forceinline__ unsigned short f2bf(float f) {
  __hip_bfloat16 h = __float2bfloat16(f);
  unsigned short u;
  __builtin_memcpy(&u, &h, 2);
  return u;
}

// ---------------------------------------------------------------------------
// Build W'[o][k'] with k' = s*Kin + i; s=0: wbase[o][i]; s=1..4: coef[i][o][s]*scaler[o].
// Also acc[o] += sum_i coef[i][o][0]  (T0 == 1 folds into bias).
// ---------------------------------------------------------------------------
__global__ __launch_bounds__(256) void build_w_kernel(
    const float* __restrict__ wbase, const float* __restrict__ coef,
    const float* __restrict__ scaler, __hip_bfloat16* __restrict__ Wp,
    float* __restrict__ acc, int Nout, int Kin)
{
  __shared__ float lds0[64][65];
  __shared__ __hip_bfloat16 ldsT[64][4][68];
  const int t = threadIdx.x;
  const int o0 = blockIdx.x * 64;
  const int i0 = blockIdx.y * 64;

  for (int r = t; r < 64 * 64 * 5; r += 256) {
    int li = r / 320;
    int rem = r - li * 320;
    int lo = rem / 5;
    int d = rem - lo * 5;
    float v = coef[((size_t)(i0 + li) * Nout + (o0 + lo)) * 5 + d];
    if (d == 0) lds0[lo][li] = v;
    else        ldsT[lo][d - 1][li] = __float2bfloat16(v);
  }
  __syncthreads();

  const size_t Kw = (size_t)5 * Kin;
  for (int r = t; r < 64 * 4 * 64; r += 256) {
    int li = r & 63;
    int d  = (r >> 6) & 3;
    int lo = r >> 8;
    float v = __bfloat162float(ldsT[lo][d][li]) * scaler[o0 + lo];
    Wp[(size_t)(o0 + lo) * Kw + (size_t)(d + 1) * Kin + i0 + li] = __float2bfloat16(v);
  }
  for (int r = t; r < 64 * 64; r += 256) {
    int li = r & 63;
    int lo = r >> 6;
    Wp[(size_t)(o0 + lo) * Kw + i0 + li] =
        __float2bfloat16(wbase[(size_t)(o0 + lo) * Kin + i0 + li]);
  }
  {
    int lo = t >> 2, q = t & 3;
    float s = 0.f;
    #pragma unroll
    for (int j = 0; j < 16; ++j) s += lds0[lo][q * 16 + j];
    s += __shfl_xor(s, 1);
    s += __shfl_xor(s, 2);
    if (q == 0) atomicAdd(&acc[o0 + lo], s);
  }
}

// ---------------------------------------------------------------------------
// A1'[b][k']: slot0 = x, slots1..4 = T_d(tanh(x)).
// ---------------------------------------------------------------------------
__global__ __launch_bounds__(256) void build_a1_kernel(
    const float* __restrict__ x, __hip_bfloat16* __restrict__ Ap, int b0)
{
  const size_t idx = ((size_t)blockIdx.x * 256 + threadIdx.x) * 4;
  const size_t row = idx >> 11;
  const int i = (int)(idx & 2047);
  const float4 xv = *(const float4*)(x + (size_t)b0 * NI + idx);
  const float xa[4] = {xv.x, xv.y, xv.z, xv.w};
  unsigned short u0[4], u1[4], u2[4], u3[4], u4[4];
  #pragma unroll
  for (int j = 0; j < 4; ++j) {
    float v  = xa[j];
    float tn = tanhf(v);
    float t2 = fmaf(2.f * tn, tn, -1.f);
    float t3 = fmaf(2.f * tn, t2, -tn);
    float t4 = fmaf(2.f * tn, t3, -t2);
    u0[j] = f2bf(v);  u1[j] = f2bf(tn); u2[j] = f2bf(t2);
    u3[j] = f2bf(t3); u4[j] = f2bf(t4);
  }
  __hip_bfloat16* bp = Ap + row * KP + i;
  *(ushort4*)(bp)          = make_ushort4(u0[0], u0[1], u0[2], u0[3]);
  *(ushort4*)(bp + NI)     = make_ushort4(u1[0], u1[1], u1[2], u1[3]);
  *(ushort4*)(bp + 2 * NI) = make_ushort4(u2[0], u2[1], u2[2], u2[3]);
  *(ushort4*)(bp + 3 * NI) = make_ushort4(u3[0], u3[1], u3[2], u3[3]);
  *(ushort4*)(bp + 4 * NI) = make_ushort4(u4[0], u4[1], u4[2], u4[3]);
}

// ---------------------------------------------------------------------------
// A2': hn = gamma*(h-mu)*rsig + beta; slot0 = hn; slots1..4 = T_d(tanh(hn)).
// ---------------------------------------------------------------------------
__global__ __launch_bounds__(256) void build_a2_kernel(
    const __hip_bfloat16* __restrict__ h, const float* __restrict__ mu,
    const float* __restrict__ rsig, const float* __restrict__ gam,
    const float* __restrict__ bet, __hip_bfloat16* __restrict__ Ap, int b0)
{
  const size_t idx = ((size_t)blockIdx.x * 256 + threadIdx.x) * 4;
  const size_t row = idx >> 11;
  const int j0 = (int)(idx & 2047);
  const ushort4 hv = *(const ushort4*)(h + (size_t)b0 * NH + idx);
  const float4 muv = *(const float4*)(mu + j0);
  const float4 rsv = *(const float4*)(rsig + j0);
  const float4 gv  = *(const float4*)(gam + j0);
  const float4 bv  = *(const float4*)(bet + j0);
  unsigned short hu[4] = {hv.x, hv.y, hv.z, hv.w};
  const float ma[4] = {muv.x, muv.y, muv.z, muv.w};
  const float ra[4] = {rsv.x, rsv.y, rsv.z, rsv.w};
  const float ga[4] = {gv.x, gv.y, gv.z, gv.w};
  const float ba[4] = {bv.x, bv.y, bv.z, bv.w};
  unsigned short u0[4], u1[4], u2[4], u3[4], u4[4];
  #pragma unroll
  for (int j = 0; j < 4; ++j) {
    __hip_bfloat16 hb;
    __builtin_memcpy(&hb, &hu[j], 2);
    float hv_f = __bfloat162float(hb);
    float hn = fmaf(ga[j] * (hv_f - ma[j]), ra[j], ba[j]);
    float tn = tanhf(hn);
    float t2 = fmaf(2.f * tn, tn, -1.f);
    float t3 = fmaf(2.f * tn, t2, -tn);
    float t4 = fmaf(2.f * tn, t3, -t2);
    u0[j] = f2bf(hn); u1[j] = f2bf(tn); u2[j] = f2bf(t2);
    u3[j] = f2bf(t3); u4[j] = f2bf(t4);
  }
  __hip_bfloat16* bp = Ap + row * KP + j0;
  *(ushort4*)(bp)          = make_ushort4(u0[0], u0[1], u0[2], u0[3]);
  *(ushort4*)(bp + NH)     = make_ushort4(u1[0], u1[1], u1[2], u1[3]);
  *(ushort4*)(bp + 2 * NH) = make_ushort4(u2[0], u2[1], u2[2], u2[3]);
  *(ushort4*)(bp + 3 * NH) = make_ushort4(u3[0], u3[1], u3[2], u3[3]);
  *(ushort4*)(bp + 4 * NH) = make_ushort4(u4[0], u4[1], u4[2], u4[3]);
}

// ---------------------------------------------------------------------------
// BatchNorm stats over bf16 h.
// ---------------------------------------------------------------------------
__global__ __launch_bounds__(256) void bn_stats_kernel(
    const __hip_bfloat16* __restrict__ h, float* __restrict__ psum,
    float* __restrict__ psq)
{
  const int col = blockIdx.x * 256 + threadIdx.x;
  const int r0 = blockIdx.y * 256;
  float s = 0.f, q = 0.f;
  for (int r = 0; r < 256; ++r) {
    float v = __bfloat162float(h[(size_t)(r0 + r) * NH + col]);
    s += v;
    q = fmaf(v, v, q);
  }
  psum[(size_t)blockIdx.y * NH + col] = s;
  psq [(size_t)blockIdx.y * NH + col] = q;
}

__global__ __launch_bounds__(256) void bn_finalize_kernel(
    const float* __restrict__ psum, const float* __restrict__ psq,
    float* __restrict__ mu, float* __restrict__ rsig)
{
  const int j = blockIdx.x * 256 + threadIdx.x;
  float s = 0.f, q = 0.f;
  for (int c = 0; c < 32; ++c) {
    s += psum[(size_t)c * NH + j];
    q += psq [(size_t)c * NH + j];
  }
  const float invB = 1.f / (float)NB;
  float m = s * invB;
  float var = fmaf(q, invB, -m * m);
  mu[j] = m;
  rsig[j] = rsqrtf(var + BNEPS);
}

// ---------------------------------------------------------------------------
// out[b][o] = b2[o] + s2[o]*acc2[o]   (bias pre-init for split-K atomic GEMM2)
// ---------------------------------------------------------------------------
__global__ __launch_bounds__(256) void bias_init_kernel(
    float* __restrict__ out, const float* __restrict__ bb,
    const float* __restrict__ bs, const float* __restrict__ bacc)
{
  const size_t idx = ((size_t)blockIdx.x * 256 + threadIdx.x) * 4;
  const int col = (int)(idx & (NO - 1));
  const float4 b = *(const float4*)(bb + col);
  const float4 s = *(const float4*)(bs + col);
  const float4 a = *(const float4*)(bacc + col);
  float4 o;
  o.x = b.x + s.x * a.x; o.y = b.y + s.y * a.y;
  o.z = b.z + s.z * a.z; o.w = b.w + s.w * a.w;
  *(float4*)(out + idx) = o;
}

// ---------------------------------------------------------------------------
// Double-buffered counted-vmcnt bf16 GEMM (B^T layout), 128x128 tile, BK=64,
// 4 waves. T2 XOR-swizzle: pre-swizzled global source (global_load_lds writes
// linearly) + swizzled ds_read col:  col ^= (row&7)*8  (involution).
// Per iter: ds_read 16 frags -> lgkmcnt(0)+barrier -> stage tile t+2 into
// freed buffer -> MFMA x32 (setprio) -> vmcnt(8 counted)+barrier.
// ATOMIC=false: C bf16 = acc + bias(n).  ATOMIC=true: f32 atomicAdd (split-K).
// ---------------------------------------------------------------------------
template<bool ATOMIC>
__global__ __launch_bounds__(256, 2) void gemm_db(
    const __hip_bfloat16* __restrict__ A, const __hip_bfloat16* __restrict__ Bm,
    void* __restrict__ Cv, const float* __restrict__ bb,
    const float* __restrict__ bs, const float* __restrict__ bacc,
    int N, int K, int nt, int lg2bps)
{
  __shared__ __attribute__((aligned(16))) __hip_bfloat16 As[2][128][64];
  __shared__ __attribute__((aligned(16))) __hip_bfloat16 Bs[2][128][64];
  const int tid  = threadIdx.x;
  const int lane = tid & 63;
  const int w    = tid >> 6;
  // XCD-bijective swizzle (grids are multiples of 8)
  int swz = ((int)blockIdx.x & 7) * ((int)gridDim.x >> 3) + ((int)blockIdx.x >> 3);
  int k0 = 0;
  if constexpr (ATOMIC) {
    const int split = swz >> lg2bps;
    swz &= (1 << lg2bps) - 1;
    k0 = split * (nt * 64);
  }
  const int nTN = N >> 7;
  const int m0 = (swz / nTN) * 128;
  const int n0 = (swz % nTN) * 128;
  const int wr = (w >> 1) * 64;
  const int wc = (w & 1) * 64;

  // staging: lane l covers row (l>>3) of an 8-row granule, 16B at swizzled col
  const int srow = lane >> 3;
  const int scol = (((lane & 7) ^ srow) * 8);
  const __hip_bfloat16* Ag = A  + (size_t)(m0 + w * 32 + srow) * K + k0 + scol;
  const __hip_bfloat16* Bg = Bm + (size_t)(n0 + w * 32 + srow) * K + k0 + scol;

  f32x4 acc[4][4];
  #pragma unroll
  for (int m = 0; m < 4; ++m)
    #pragma unroll
    for (int n = 0; n < 4; ++n) {
      f32x4 z = {0.f, 0.f, 0.f, 0.f};
      acc[m][n] = z;
    }

  const int fr = lane & 15;
  const int kg = (lane >> 4) * 8;
  const int swz_r = (fr & 7) * 8;

  #define STAGE(buf, kt)                                                     \
    do {                                                                     \
      _Pragma("unroll")                                                      \
      for (int c = 0; c < 4; ++c)                                            \
        load_lds16(Ag + (size_t)c * 8 * K + (kt), &As[buf][w * 32 + c * 8][0]); \
      _Pragma("unroll")                                                      \
      for (int c = 0; c < 4; ++c)                                            \
        load_lds16(Bg + (size_t)c * 8 * K + (kt), &Bs[buf][w * 32 + c * 8][0]); \
    } while (0)

  // Prologue: stage tiles 0 and 1; wait for tile 0 only (counted).
  STAGE(0, 0);
  STAGE(1, 64);
  asm volatile("s_waitcnt vmcnt(8)" ::: "memory");
  __builtin_amdgcn_s_barrier();

  for (int it = 0; it < nt; ++it) {
    const int cur = it & 1;
    bf16x8 af[4][2], bfr[4][2];
    #pragma unroll
    for (int m = 0; m < 4; ++m)
      #pragma unroll
      for (int kk = 0; kk < 2; ++kk)
        af[m][kk] = *(const bf16x8*)&As[cur][wr + m * 16 + fr][(kk * 32 + kg) ^ swz_r];
    #pragma unroll
    for (int n = 0; n < 4; ++n)
      #pragma unroll
      for (int kk = 0; kk < 2; ++kk)
        bfr[n][kk] = *(const bf16x8*)&Bs[cur][wc + n * 16 + fr][(kk * 32 + kg) ^ swz_r];
    // All frag reads done -> buffer free for restaging after the barrier.
    asm volatile("s_waitcnt lgkmcnt(0)" ::: "memory");
    __builtin_amdgcn_s_barrier();
    const bool pre = (it + 2 < nt);
    if (pre) STAGE(cur, (it + 2) * 64);
    __builtin_amdgcn_s_setprio(1);
    #pragma unroll
    for (int m = 0; m < 4; ++m)
      #pragma unroll
      for (int n = 0; n < 4; ++n)
        #pragma unroll
        for (int kk = 0; kk < 2; ++kk)
          acc[m][n] = __builtin_amdgcn_mfma_f32_16x16x32_bf16(
              af[m][kk], bfr[n][kk], acc[m][n], 0, 0, 0);
    __builtin_amdgcn_s_setprio(0);
    // Counted wait: tile it+1 (issued last iter) landed; tile it+2 in flight.
    if (pre) asm volatile("s_waitcnt vmcnt(8)" ::: "memory");
    else     asm volatile("s_waitcnt vmcnt(0)" ::: "memory");
    __builtin_amdgcn_s_barrier();
  }
  #undef STAGE

  const int cr = (lane >> 4) * 4;
  const int cc = lane & 15;
  if constexpr (ATOMIC) {
    float* C = (float*)Cv;
    #pragma unroll
    for (int n = 0; n < 4; ++n) {
      const int col = n0 + wc + n * 16 + cc;
      #pragma unroll
      for (int m = 0; m < 4; ++m) {
        float* Cp = C + (size_t)(m0 + wr + m * 16 + cr) * N + col;
        #pragma unroll
        for (int r = 0; r < 4; ++r)
          atomicAdd(&Cp[(size_t)r * N], acc[m][n][r]);
      }
    }
  } else {
    __hip_bfloat16* C = (__hip_bfloat16*)Cv;
    #pragma unroll
    for (int n = 0; n < 4; ++n) {
      const int col = n0 + wc + n * 16 + cc;
      const float bias = bb[col] + bs[col] * bacc[col];
      #pragma unroll
      for (int m = 0; m < 4; ++m) {
        __hip_bfloat16* Cp = C + (size_t)(m0 + wr + m * 16 + cr) * N + col;
        #pragma unroll
        for (int r = 0; r < 4; ++r)
          Cp[(size_t)r * N] = __float2bfloat16(acc[m][n][r] + bias);
      }
    }
  }
}

// ---------------------------------------------------------------------------
extern "C" void kernel_launch(void* const* d_in, const int* in_sizes, int n_in,
                              void* d_out, int out_size, void* d_ws, size_t ws_size,
                              hipStream_t stream) {
  (void)in_sizes; (void)n_in; (void)out_size;
  const float* x   = (const float*)d_in[0];
  const float* w1  = (const float*)d_in[1];
  const float* b1  = (const float*)d_in[2];
  const float* c1  = (const float*)d_in[3];
  const float* s1  = (const float*)d_in[4];
  const float* gam = (const float*)d_in[5];
  const float* bet = (const float*)d_in[6];
  const float* w2  = (const float*)d_in[7];
  const float* b2  = (const float*)d_in[8];
  const float* c2  = (const float*)d_in[9];
  const float* s2  = (const float*)d_in[10];
  float* out = (float*)d_out;

  const bool full = ws_size >= 243820544ULL;
  const size_t apBytes = full ? 167772160ULL : 83886080ULL;
  char* ws = (char*)d_ws;
  __hip_bfloat16* Ap = (__hip_bfloat16*)ws;
  __hip_bfloat16* Wp = (__hip_bfloat16*)(ws + apBytes);
  __hip_bfloat16* hb = (__hip_bfloat16*)(ws + apBytes + 41943040ULL);
  char* tail = ws + apBytes + 41943040ULL + 33554432ULL;
  float* acc1 = (float*)(tail);
  float* acc2 = (float*)(tail + 8192);
  float* psum = (float*)(tail + 10240);
  float* psq  = (float*)(tail + 272384);
  float* mu   = (float*)(tail + 534528);
  float* rsig = (float*)(tail + 542720);

  dim3 blk(256);
  hipMemsetAsync(acc1, 0, 8192 + 2048, stream);

  // Layer 1 weights + bias-acc
  build_w_kernel<<<dim3(NH / 64, NI / 64), blk, 0, stream>>>(w1, c1, s1, Wp, acc1, NH, NI);

  if (full) {
    build_a1_kernel<<<(NB * NI / 4) / 256, blk, 0, stream>>>(x, Ap, 0);
    gemm_db<false><<<(NB / 128) * (NH / 128), blk, 0, stream>>>(
        Ap, Wp, hb, b1, s1, acc1, NH, KP, KP / 64, 0);
  } else {
    for (int ch = 0; ch < 2; ++ch) {
      int b0 = ch * CHNK;
      build_a1_kernel<<<(CHNK * NI / 4) / 256, blk, 0, stream>>>(x, Ap, b0);
      gemm_db<false><<<(CHNK / 128) * (NH / 128), blk, 0, stream>>>(
          Ap, Wp, hb + (size_t)b0 * NH, b1, s1, acc1, NH, KP, KP / 64, 0);
    }
  }

  // BatchNorm statistics
  bn_stats_kernel<<<dim3(NH / 256, 32), blk, 0, stream>>>(hb, psum, psq);
  bn_finalize_kernel<<<NH / 256, blk, 0, stream>>>(psum, psq, mu, rsig);

  // Layer 2 weights + bias-acc (Wp reused)
  build_w_kernel<<<dim3(NO / 64, NH / 64), blk, 0, stream>>>(w2, c2, s2, Wp, acc2, NO, NH);

  // Pre-init out with bias, then split-K=4 atomic GEMM2
  bias_init_kernel<<<(NB * NO / 4) / 256, blk, 0, stream>>>(out, b2, s2, acc2);

  if (full) {
    build_a2_kernel<<<(NB * NH / 4) / 256, blk, 0, stream>>>(hb, mu, rsig, gam, bet, Ap, 0);
    // 4 splits x 256 blocks = 1024; lg2bps=8; nt=40 (K2=2560)
    gemm_db<true><<<4 * (NB / 128) * (NO / 128), blk, 0, stream>>>(
        Ap, Wp, out, nullptr, nullptr, nullptr, NO, KP, (KP / 4) / 64, 8);
  } else {
    for (int ch = 0; ch < 2; ++ch) {
      int b0 = ch * CHNK;
      build_a2_kernel<<<(CHNK * NH / 4) / 256, blk, 0, stream>>>(hb, mu, rsig, gam, bet, Ap, b0);
      gemm_db<true><<<4 * (CHNK / 128) * (NO / 128), blk, 0, stream>>>(
          Ap, Wp, out + (size_t)b0 * NO, nullptr, nullptr, nullptr, NO, KP, (KP / 4) / 64, 7);
    }
  }
}